// Round 21
// baseline (513.389 us; speedup 1.0000x reference)
//
#include <hip/hip_runtime.h>
#include <hip/hip_bf16.h>
#include <math.h>
#include <stdint.h>

#define DIM 1024
#define FF 4096
#define NE 8
#define NTOK 8192
#define NASSIGN (NTOK * 2)
#define MB_MAX (NTOK / 256)     // 32 max m-blocks per expert
#define YPN ((size_t)NASSIGN * DIM)   // elements per bf16 partial (33.55 MB)

typedef short short8 __attribute__((ext_vector_type(8)));
typedef short short4v __attribute__((ext_vector_type(4)));
typedef float f32x4 __attribute__((ext_vector_type(4)));

static __device__ __forceinline__ short bf16_of(float f) {
    union { float f; unsigned u; } v; v.f = f;
    unsigned r = v.u + 0x7fffu + ((v.u >> 16) & 1u);   // RNE
    return (short)(r >> 16);
}

static __device__ __forceinline__ float f_of_bf16(short s) {
    union { unsigned u; float f; } v; v.u = ((unsigned)(unsigned short)s) << 16;
    return v.f;
}

static __device__ __forceinline__ short8 cvt8(float4 a, float4 b) {
    short8 r;
    r[0] = bf16_of(a.x); r[1] = bf16_of(a.y); r[2] = bf16_of(a.z); r[3] = bf16_of(a.w);
    r[4] = bf16_of(b.x); r[5] = bf16_of(b.y); r[6] = bf16_of(b.z); r[7] = bf16_of(b.w);
    return r;
}

static __device__ __forceinline__ void gl_lds16(const short* g, short* lds) {
    __builtin_amdgcn_global_load_lds(
        (const __attribute__((address_space(1))) void*)g,
        (__attribute__((address_space(3))) void*)lds, 16, 0, 0);
}

// fast exact-form gelu: Abramowitz-Stegun 7.1.26 erf approx, |err| < 1.5e-7
static __device__ __forceinline__ float gelu_f(float x) {
    float z = x * 0.70710678118f;
    float az = fabsf(z);
    float t = __builtin_amdgcn_rcpf(1.f + 0.3275911f * az);
    float poly = t * (0.254829592f + t * (-0.284496736f + t * (1.421413741f +
                 t * (-1.453152027f + t * 1.061405429f))));
    float e = __expf(-z * z);
    float erfv = 1.f - poly * e;
    erfv = (z < 0.f) ? -erfv : erfv;
    return 0.5f * x * (1.f + erfv);
}

// ------------- fused prep: router (blocks 0..RTR-1, NO atomics) || weight cvt -------------
#define RTR_BLOCKS (NTOK / 4)            // 2048
__global__ __launch_bounds__(256) void prep_k(const float* __restrict__ x,
                                              const float* __restrict__ Wr,
                                              int* __restrict__ a_exp, float* __restrict__ a_w,
                                              short* __restrict__ xb,
                                              const float* __restrict__ W1,
                                              const float* __restrict__ W2,
                                              short* __restrict__ W1b,
                                              short* __restrict__ W2b,
                                              int n8a, int n8tot) {
    if (blockIdx.x >= RTR_BLOCKS) {
        int i = (blockIdx.x - RTR_BLOCKS) * 256 + threadIdx.x;
        if (i >= n8tot) return;
        const float* in; short* out; int j;
        if (i < n8a) { in = W1; out = W1b; j = i; }
        else         { in = W2; out = W2b; j = i - n8a; }
        float4 a = ((const float4*)in)[2 * j];
        float4 b = ((const float4*)in)[2 * j + 1];
        ((short8*)out)[j] = cvt8(a, b);
        return;
    }
    // router: 4 token-waves per block; emits top-2 (a_exp, a_w) + xb. Zero atomics.
    int t = blockIdx.x * 4 + (threadIdx.x >> 6);
    int lane = threadIdx.x & 63;
    const float* xr = x + (size_t)t * DIM;
    short* xbr = xb + (size_t)t * DIM;
    float p[NE];
#pragma unroll
    for (int e = 0; e < NE; ++e) p[e] = 0.f;
    for (int i = 0; i < DIM / 64; ++i) {
        float xv = xr[lane + i * 64];
        xbr[lane + i * 64] = bf16_of(xv);
#pragma unroll
        for (int e = 0; e < NE; ++e) p[e] += xv * Wr[e * DIM + lane + i * 64];
    }
#pragma unroll
    for (int off = 32; off >= 1; off >>= 1)
#pragma unroll
        for (int e = 0; e < NE; ++e) p[e] += __shfl_xor(p[e], off);
    if (lane == 0) {
        float mx = p[0];
#pragma unroll
        for (int e = 1; e < NE; ++e) mx = fmaxf(mx, p[e]);
        float pr[NE]; float s = 0.f;
#pragma unroll
        for (int e = 0; e < NE; ++e) { pr[e] = expf(p[e] - mx); s += pr[e]; }
#pragma unroll
        for (int e = 0; e < NE; ++e) pr[e] /= s;
        int i1 = 0;
#pragma unroll
        for (int e = 1; e < NE; ++e) if (pr[e] > pr[i1]) i1 = e;
        int i2 = (i1 == 0) ? 1 : 0;
#pragma unroll
        for (int e = 0; e < NE; ++e) if (e != i1 && pr[e] > pr[i2]) i2 = e;
        float w1 = pr[i1], w2 = pr[i2], nrm = w1 + w2;
        a_exp[2 * t] = i1;     a_w[2 * t] = w1 / nrm;
        a_exp[2 * t + 1] = i2; a_w[2 * t + 1] = w2 / nrm;
    }
}

// ------- rank_k: deterministic bucketing, single 1024-thread block, no atomics -------
#define RK_T 1024
#define RK_IT (NASSIGN / RK_T)           // 16
__global__ __launch_bounds__(RK_T) void rank_k(const int* __restrict__ a_exp,
                                               int* __restrict__ cnt,
                                               int* __restrict__ offs,
                                               int* __restrict__ ptok,
                                               int* __restrict__ slot_of) {
    __shared__ int s[NE][RK_T];
    __shared__ int cur[NE][RK_T];
    __shared__ int offs_s[NE];
    const int tid = threadIdx.x;
    const int base = tid * RK_IT;
#pragma unroll
    for (int e = 0; e < NE; ++e) s[e][tid] = 0;
    for (int k = 0; k < RK_IT; ++k) s[a_exp[base + k]][tid]++;   // own column, no race
    __syncthreads();
    for (int d = 1; d < RK_T; d <<= 1) {
        int v[NE];
#pragma unroll
        for (int e = 0; e < NE; ++e) v[e] = (tid >= d) ? s[e][tid - d] : 0;
        __syncthreads();
#pragma unroll
        for (int e = 0; e < NE; ++e) s[e][tid] += v[e];
        __syncthreads();
    }
    if (tid == 0) {
        int acc = 0;
#pragma unroll
        for (int e = 0; e < NE; ++e) { offs_s[e] = acc; offs[e] = acc; acc += s[e][RK_T - 1]; }
        offs[NE] = acc;
    }
    if (tid < NE) cnt[tid] = s[tid][RK_T - 1];
    __syncthreads();
#pragma unroll
    for (int e = 0; e < NE; ++e)
        cur[e][tid] = offs_s[e] + ((tid >= 1) ? s[e][tid - 1] : 0);
    for (int k = 0; k < RK_IT; ++k) {
        int a = base + k;
        int e = a_exp[a];
        int r = cur[e][tid]++;
        ptok[r] = a >> 1;
        slot_of[a] = r;
    }
}

// ======== 256x256 grouped GEMM core — rotated read-ahead, 1 vmcnt/K-tile (r9, verified) ========
// LDS: 2 K-tile buffers (A 256x64 + B 256x64 bf16) = 128 KB. 8 waves (2M x 4N).
// Swizzle: LDS[row][slot] = global[row][slot ^ (row&7)]  -> 0 bank conflicts (verified).
// Cross-wave publication: wave X's vmcnt(4) @p2(t) drains Ah0_{t+1},Ba_{t+1}; p2's
// barrier orders every wave's drain before any wave's p4 rotate-reads. LDS WAR windows
// all span >=2 sealed barriers (r9 audit). n0-fast decomposition (r14 lesson).
#define MFMA_BF16 __builtin_amdgcn_mfma_f32_16x16x32_bf16
#define SBAR0 __builtin_amdgcn_sched_barrier(0)
#define LGKM0 asm volatile("s_waitcnt lgkmcnt(0)" ::: "memory")

template <int KROW, int KCH, bool GATHER>
__device__ __forceinline__ void gemm8p(const short* __restrict__ A,
                                       const int* __restrict__ ptok,
                                       const short* __restrict__ B,
                                       int offs_e, int cnt_e, int m0, int n0, int k0,
                                       f32x4 acc[8][4],
                                       short (*As)[16384], short (*Bs)[16384]) {
    const int tid = threadIdx.x;
    const int lane = tid & 63, wave = tid >> 6;
    const int wr = wave >> 2, wc = wave & 3;

#pragma unroll
    for (int m = 0; m < 8; ++m)
#pragma unroll
        for (int n = 0; n < 4; ++n) acc[m][n] = (f32x4){0.f, 0.f, 0.f, 0.f};

    const int srow = tid >> 3, sslot = tid & 7;
    const int gsl8 = (sslot ^ (srow & 7)) * 8;      // inverse-swizzled global 16B slot

    int ra0 = m0 + srow;       if (ra0 >= cnt_e) ra0 = cnt_e - 1;   // Ah0
    int ra2 = m0 + srow + 128; if (ra2 >= cnt_e) ra2 = cnt_e - 1;   // Ah0
    int ra1 = m0 + srow + 64;  if (ra1 >= cnt_e) ra1 = cnt_e - 1;   // Ah1
    int ra3 = m0 + srow + 192; if (ra3 >= cnt_e) ra3 = cnt_e - 1;   // Ah1
    const short* aR0 = A + (GATHER ? (size_t)ptok[offs_e + ra0] : (size_t)(offs_e + ra0)) * KROW + k0 + gsl8;
    const short* aR2 = A + (GATHER ? (size_t)ptok[offs_e + ra2] : (size_t)(offs_e + ra2)) * KROW + k0 + gsl8;
    const short* aR1 = A + (GATHER ? (size_t)ptok[offs_e + ra1] : (size_t)(offs_e + ra1)) * KROW + k0 + gsl8;
    const short* aR3 = A + (GATHER ? (size_t)ptok[offs_e + ra3] : (size_t)(offs_e + ra3)) * KROW + k0 + gsl8;
    const int br = (srow & 31) + (srow >> 5) * 64;
    const short* bRa0 = B + (size_t)(n0 + br) * KROW + k0 + gsl8;
    const short* bRa1 = B + (size_t)(n0 + br + 128) * KROW + k0 + gsl8;
    const short* bRb0 = B + (size_t)(n0 + br + 32) * KROW + k0 + gsl8;
    const short* bRb1 = B + (size_t)(n0 + br + 160) * KROW + k0 + gsl8;
    const int lA0a = tid * 8,                 lA0b = (tid + 1024) * 8;
    const int lA1a = (tid + 512) * 8,         lA1b = (tid + 1536) * 8;
    const int lBaa = (br * 8 + sslot) * 8,    lBab = ((br + 128) * 8 + sslot) * 8;
    const int lBba = ((br + 32) * 8 + sslot) * 8, lBbb = ((br + 160) * 8 + sslot) * 8;

    auto stAh0 = [&](int b, int co) { gl_lds16(aR0 + co, &As[b][lA0a]); gl_lds16(aR2 + co, &As[b][lA0b]); };
    auto stAh1 = [&](int b, int co) { gl_lds16(aR1 + co, &As[b][lA1a]); gl_lds16(aR3 + co, &As[b][lA1b]); };
    auto stBa  = [&](int b, int co) { gl_lds16(bRa0 + co, &Bs[b][lBaa]); gl_lds16(bRa1 + co, &Bs[b][lBab]); };
    auto stBb  = [&](int b, int co) { gl_lds16(bRb0 + co, &Bs[b][lBba]); gl_lds16(bRb1 + co, &Bs[b][lBbb]); };

    const int fr = lane & 15, g4 = lane >> 4, swz = fr & 7;
    const int NK = KCH / 64;

    short8 aF0[2][4], aF1[2][4], bF01[2][2], bF23[2][2];

    auto rdA0 = [&](const short* P) {
#pragma unroll
        for (int ks = 0; ks < 2; ++ks)
#pragma unroll
            for (int m = 0; m < 4; ++m)
                aF0[ks][m] = *(const short8*)&P[((wr * 128 + m * 16 + fr) * 8 + ((ks * 4 + g4) ^ swz)) * 8];
    };
    auto rdA1 = [&](const short* P) {
#pragma unroll
        for (int ks = 0; ks < 2; ++ks)
#pragma unroll
            for (int m = 0; m < 4; ++m)
                aF1[ks][m] = *(const short8*)&P[((wr * 128 + 64 + m * 16 + fr) * 8 + ((ks * 4 + g4) ^ swz)) * 8];
    };
    auto rdB01 = [&](const short* P) {
#pragma unroll
        for (int ks = 0; ks < 2; ++ks)
#pragma unroll
            for (int n = 0; n < 2; ++n)
                bF01[ks][n] = *(const short8*)&P[((wc * 64 + n * 16 + fr) * 8 + ((ks * 4 + g4) ^ swz)) * 8];
    };
    auto rdB23 = [&](const short* P) {
#pragma unroll
        for (int ks = 0; ks < 2; ++ks)
#pragma unroll
            for (int n = 0; n < 2; ++n)
                bF23[ks][n] = *(const short8*)&P[((wc * 64 + (n + 2) * 16 + fr) * 8 + ((ks * 4 + g4) ^ swz)) * 8];
    };

    // prologue: tile0 (4 halves) + tile1's Ah0,Ba; vmcnt(4) covers tile0 entirely
    stAh0(0, 0); stBa(0, 0); stBb(0, 0); stAh1(0, 0);
    if (NK > 1) {
        stAh0(1, 64); stBa(1, 64);
        asm volatile("s_waitcnt vmcnt(4)" ::: "memory");
    } else {
        asm volatile("s_waitcnt vmcnt(0)" ::: "memory");
    }
    SBAR0;
    __builtin_amdgcn_s_barrier();
    rdA0(As[0]); rdB01(Bs[0]);      // tile0 p1 frags (drained by p1's LGKM0)

    for (int t = 0; t < NK; ++t) {
        const int cur = t & 1, nxt = cur ^ 1;
        const short* Ab = As[cur];
        const short* Bb2 = Bs[cur];
        const int co1 = (t + 1) * 64, co2 = (t + 2) * 64;
        const bool pf1 = (t + 1 < NK), pf2 = (t + 2 < NK);

        // ---- P1: MFMA mh0 x n01; read Bn23_t; stage Bb_{t+1} ----
        LGKM0; SBAR0;
        __builtin_amdgcn_s_setprio(1);
#pragma unroll
        for (int ks = 0; ks < 2; ++ks)
#pragma unroll
            for (int m = 0; m < 4; ++m)
#pragma unroll
                for (int n = 0; n < 2; ++n)
                    acc[m][n] = MFMA_BF16(aF0[ks][m], bF01[ks][n], acc[m][n], 0, 0, 0);
        __builtin_amdgcn_s_setprio(0);
        rdB23(Bb2);
        if (pf1) stBb(nxt, co1);
        SBAR0;
        __builtin_amdgcn_s_barrier();

        // ---- P2: MFMA mh0 x n23; read Ah1_t; stage Ah1_{t+1}; vmcnt publishes t+1 ----
        LGKM0; SBAR0;
        __builtin_amdgcn_s_setprio(1);
#pragma unroll
        for (int ks = 0; ks < 2; ++ks)
#pragma unroll
            for (int m = 0; m < 4; ++m)
#pragma unroll
                for (int n = 0; n < 2; ++n)
                    acc[m][n + 2] = MFMA_BF16(aF0[ks][m], bF23[ks][n], acc[m][n + 2], 0, 0, 0);
        __builtin_amdgcn_s_setprio(0);
        rdA1(Ab);
        if (pf1) stAh1(nxt, co1);
        SBAR0;
        __builtin_amdgcn_s_barrier();

        // ---- P3: MFMA mh1 x n01; stage Ah0_{t+2} (into cur) ----
        LGKM0; SBAR0;
        __builtin_amdgcn_s_setprio(1);
#pragma unroll
        for (int ks = 0; ks < 2; ++ks)
#pragma unroll
            for (int m = 0; m < 4; ++m)
#pragma unroll
                for (int n = 0; n < 2; ++n)
                    acc[4 + m][n] = MFMA_BF16(aF1[ks][m], bF01[ks][n], acc[4 + m][n], 0, 0, 0);
        __builtin_amdgcn_s_setprio(0);
        if (pf2) stAh0(cur, co2);
        SBAR0;
        __builtin_amdgcn_s_barrier();

        // ---- P4: MFMA mh1 x n23; stage Ba_{t+2}; vmcnt; read tile t+1 p1 frags ----
        __builtin_amdgcn_s_setprio(1);
#pragma unroll
        for (int ks = 0; ks < 2; ++ks)
#pragma unroll
            for (int m = 0; m < 4; ++m)
#pragma unroll
                for (int n = 0; n < 2; ++n)
                    acc[4 + m][n + 2] = MFMA_BF16(aF1[ks][m], bF23[ks][n], acc[4 + m][n + 2], 0, 0, 0);
        __builtin_amdgcn_s_setprio(0);
        if (pf2) {
            stBa(cur, co2);
            asm volatile("s_waitcnt vmcnt(4)" ::: "memory");
        } else if (pf1) {
            asm volatile("s_waitcnt vmcnt(0)" ::: "memory");
        }
        SBAR0;
        if (pf1) { rdA0(As[nxt]); rdB01(Bs[nxt]); }
        SBAR0;
        __builtin_amdgcn_s_barrier();
    }
}

// ---------------- GEMM1: H = gelu(Xg @ W1[e]^T + b1[e]) ----------------
#define G1_NX (FF / 256)                 // 16
#define G1_NWG (G1_NX * MB_MAX * NE)     // 4096
__global__ __launch_bounds__(512, 2) void gemm1_k(const short* __restrict__ xb,
                                                  const short* __restrict__ W1b,
                                                  const float* __restrict__ b1,
                                                  const int* __restrict__ cnt,
                                                  const int* __restrict__ offs,
                                                  const int* __restrict__ ptok,
                                                  short* __restrict__ H) {
    __shared__ __align__(16) short As[2][16384];
    __shared__ __align__(16) short Bs[2][16384];
    int wg = (blockIdx.x % 8) * (G1_NWG / 8) + blockIdx.x / 8;   // bijective XCD swizzle
    const int n0 = (wg % G1_NX) * 256;  wg /= G1_NX;             // n0 fast (A-panel L2 reuse)
    const int m0 = (wg % MB_MAX) * 256; wg /= MB_MAX;
    const int e = wg;
    const int cnt_e = cnt[e];
    if (m0 >= cnt_e) return;
    const int offs_e = offs[e];

    f32x4 acc[8][4];
    gemm8p<DIM, DIM, true>(xb, ptok, W1b + (size_t)e * FF * DIM, offs_e, cnt_e, m0, n0, 0, acc, As, Bs);

    const int lane = threadIdx.x & 63, wave = threadIdx.x >> 6;
    const int wr = wave >> 2, wc = wave & 3;
    const int colb = lane & 15, rowb = (lane >> 4) * 4;
    float b1v[4];
#pragma unroll
    for (int n = 0; n < 4; ++n) b1v[n] = b1[e * FF + n0 + wc * 64 + n * 16 + colb];
#pragma unroll
    for (int m = 0; m < 8; ++m) {
#pragma unroll
        for (int r = 0; r < 4; ++r) {
            const int gm = m0 + wr * 128 + m * 16 + rowb + r;
            if (gm >= cnt_e) continue;
#pragma unroll
            for (int n = 0; n < 4; ++n) {
                const int col = n0 + wc * 64 + n * 16 + colb;
                float v = gelu_f(acc[m][n][r] + b1v[n]);
                H[(size_t)(offs_e + gm) * FF + col] = bf16_of(v);
            }
        }
    }
}

// ---- GEMM2: ypart(bf16)[kslice] = H[:, kslice] @ W2[e][:, kslice]^T (b2 in combine) ----
// Partials 0,1 live in W1b (dead after gemm1; 67.1 MB = exactly 2 partials).
// Partials 2,3 (ks=4 only) live in the separate ypB allocation.
#define G2_NX (DIM / 256)                // 4
template <int KCH>
__global__ __launch_bounds__(512, 2) void gemm2_k(const short* __restrict__ H,
                                                  const short* __restrict__ W2b,
                                                  const int* __restrict__ cnt,
                                                  const int* __restrict__ offs,
                                                  short* __restrict__ ypA,
                                                  short* __restrict__ ypB,
                                                  int nwg) {
    __shared__ __align__(16) short As[2][16384];
    __shared__ __align__(16) short Bs[2][16384];
    const int KS = FF / KCH;
    int wg = (blockIdx.x % 8) * (nwg / 8) + blockIdx.x / 8;
    int nk = wg % (G2_NX * KS); wg /= (G2_NX * KS);              // (n,k) fast (A-panel reuse)
    const int n0 = (nk % G2_NX) * 256;
    const int kslice = nk / G2_NX;
    const int m0 = (wg % MB_MAX) * 256; wg /= MB_MAX;
    const int e = wg;
    const int cnt_e = cnt[e];
    if (m0 >= cnt_e) return;
    const int offs_e = offs[e];

    f32x4 acc[8][4];
    gemm8p<FF, KCH, false>(H, nullptr, W2b + (size_t)e * DIM * FF, offs_e, cnt_e, m0, n0,
                           kslice * KCH, acc, As, Bs);

    short* y = (kslice < 2) ? (ypA + (size_t)kslice * YPN)
                            : (ypB + (size_t)(kslice - 2) * YPN);
    const int lane = threadIdx.x & 63, wave = threadIdx.x >> 6;
    const int wr = wave >> 2, wc = wave & 3;
    const int colb = lane & 15, rowb = (lane >> 4) * 4;
#pragma unroll
    for (int m = 0; m < 8; ++m) {
#pragma unroll
        for (int r = 0; r < 4; ++r) {
            const int gm = m0 + wr * 128 + m * 16 + rowb + r;
            if (gm >= cnt_e) continue;
#pragma unroll
            for (int n = 0; n < 4; ++n) {
                const int col = n0 + wc * 64 + n * 16 + colb;
                y[(size_t)(offs_e + gm) * DIM + col] = bf16_of(acc[m][n][r]);
            }
        }
    }
}

// -- combine (grid-strided): out[t] = w1*(sum_k yp[k][s1]+b2[e1]) + w2*(...) --
__global__ __launch_bounds__(256) void combine_k(const short* __restrict__ ypA,
                                                 const short* __restrict__ ypB,
                                                 int ksn,
                                                 const int* __restrict__ slot_of,
                                                 const int* __restrict__ a_exp,
                                                 const float* __restrict__ a_w,
                                                 const float* __restrict__ b2,
                                                 float* __restrict__ out) {
    const int c = threadIdx.x;          // 256 threads * 4 cols = 1024
    for (int t = blockIdx.x; t < NTOK; t += 2048) {
        const int s1 = slot_of[2 * t], s2 = slot_of[2 * t + 1];
        const int e1 = a_exp[2 * t], e2 = a_exp[2 * t + 1];
        const float w1 = a_w[2 * t], w2 = a_w[2 * t + 1];
        float v1x = 0.f, v1y = 0.f, v1z = 0.f, v1w = 0.f;
        float v2x = 0.f, v2y = 0.f, v2z = 0.f, v2w = 0.f;
        for (int k = 0; k < ksn; ++k) {
            const short* yk = (k < 2) ? (ypA + (size_t)k * YPN)
                                      : (ypB + (size_t)(k - 2) * YPN);
            short4v p1 = ((const short4v*)(yk + (size_t)s1 * DIM))[c];
            short4v p2 = ((const short4v*)(yk + (size_t)s2 * DIM))[c];
            v1x += f_of_bf16(p1[0]); v1y += f_of_bf16(p1[1]); v1z += f_of_bf16(p1[2]); v1w += f_of_bf16(p1[3]);
            v2x += f_of_bf16(p2[0]); v2y += f_of_bf16(p2[1]); v2z += f_of_bf16(p2[2]); v2w += f_of_bf16(p2[3]);
        }
        float4 g1 = ((const float4*)(b2 + (size_t)e1 * DIM))[c];
        float4 g2 = ((const float4*)(b2 + (size_t)e2 * DIM))[c];
        float4 o;
        o.x = w1 * (v1x + g1.x) + w2 * (v2x + g2.x);
        o.y = w1 * (v1y + g1.y) + w2 * (v2y + g2.y);
        o.z = w1 * (v1z + g1.z) + w2 * (v2z + g2.z);
        o.w = w1 * (v1w + g1.w) + w2 * (v2w + g2.w);
        ((float4*)(out + (size_t)t * DIM))[c] = o;
    }
}

// ---------------- launch ----------------
extern "C" void kernel_launch(void* const* d_in, const int* in_sizes, int n_in,
                              void* d_out, int out_size, void* d_ws, size_t ws_size,
                              hipStream_t stream) {
    const float* x  = (const float*)d_in[0];
    const float* Wr = (const float*)d_in[1];
    const float* W1 = (const float*)d_in[2];
    const float* b1 = (const float*)d_in[3];
    const float* W2 = (const float*)d_in[4];
    const float* b2 = (const float*)d_in[5];
    float* out = (float*)d_out;

    char* w = (char*)d_ws;
    int*   cnt     = (int*)w;                        // 32 B
    int*   offs    = (int*)(w + 64);                 // 36 B
    int*   a_exp   = (int*)(w + 128);
    int*   ptok    = a_exp + NASSIGN;
    int*   slot_of = ptok + NASSIGN;
    float* a_w     = (float*)(slot_of + NASSIGN);
    char*  p       = (char*)(a_w + NASSIGN);
    p = (char*)(((uintptr_t)p + 255) & ~(uintptr_t)255);
    short* xb  = (short*)p;                p += (size_t)NTOK * DIM * 2;
    short* W1b = (short*)p;                p += (size_t)NE * FF * DIM * 2;   // 67.1 MB
    short* W2b = (short*)p;                p += (size_t)NE * DIM * FF * 2;   // 67.1 MB
    short* H   = (short*)p;                p += (size_t)NASSIGN * FF * 2;    // 134.2 MB
    // ypA aliases W1b (dead after gemm1): exactly 2 bf16 partials (2 x 33.55 MB).
    short* ypA = (short*)W1b;
    // ypB: partials 2,3 for ks=4 (67.1 MB). Footprint with ypB == r13's proven 352 MB.
    short* ypB = (short*)p;                char* p4 = p + 2 * YPN * 2;
    const int ksn = ((size_t)(p4 - w) <= ws_size) ? 4 : 2;

    const int n8a = NE * FF * DIM / 8, n8tot = n8a + NE * DIM * FF / 8;
    const int prep_blocks = RTR_BLOCKS + (n8tot + 255) / 256;
    prep_k<<<prep_blocks, 256, 0, stream>>>(x, Wr, a_exp, a_w, xb,
                                            W1, W2, W1b, W2b, n8a, n8tot);

    rank_k<<<1, RK_T, 0, stream>>>(a_exp, cnt, offs, ptok, slot_of);

    gemm1_k<<<G1_NWG, 512, 0, stream>>>(xb, W1b, b1, cnt, offs, ptok, H);

    if (ksn == 4) {
        const int nwg2 = G2_NX * 4 * MB_MAX * NE;   // 4096
        gemm2_k<FF / 4><<<nwg2, 512, 0, stream>>>(H, W2b, cnt, offs, ypA, ypB, nwg2);
    } else {
        const int nwg2 = G2_NX * 2 * MB_MAX * NE;   // 2048; both partials inside W1b
        gemm2_k<FF / 2><<<nwg2, 512, 0, stream>>>(H, W2b, cnt, offs, ypA, ypB, nwg2);
    }
    combine_k<<<2048, 256, 0, stream>>>(ypA, ypB, ksn, slot_of, a_exp, a_w, b2, out);
}

// Round 22
// 505.291 us; speedup vs baseline: 1.0160x; 1.0160x over previous
//
#include <hip/hip_runtime.h>
#include <hip/hip_bf16.h>
#include <math.h>
#include <stdint.h>

#define DIM 1024
#define FF 4096
#define NE 8
#define NTOK 8192
#define NASSIGN (NTOK * 2)
#define MB_MAX (NTOK / 256)     // 32 max m-blocks per expert

typedef short short8 __attribute__((ext_vector_type(8)));
typedef short short4v __attribute__((ext_vector_type(4)));
typedef float f32x4 __attribute__((ext_vector_type(4)));

static __device__ __forceinline__ short bf16_of(float f) {
    union { float f; unsigned u; } v; v.f = f;
    unsigned r = v.u + 0x7fffu + ((v.u >> 16) & 1u);   // RNE
    return (short)(r >> 16);
}

static __device__ __forceinline__ float f_of_bf16(short s) {
    union { unsigned u; float f; } v; v.u = ((unsigned)(unsigned short)s) << 16;
    return v.f;
}

static __device__ __forceinline__ short8 cvt8(float4 a, float4 b) {
    short8 r;
    r[0] = bf16_of(a.x); r[1] = bf16_of(a.y); r[2] = bf16_of(a.z); r[3] = bf16_of(a.w);
    r[4] = bf16_of(b.x); r[5] = bf16_of(b.y); r[6] = bf16_of(b.z); r[7] = bf16_of(b.w);
    return r;
}

static __device__ __forceinline__ void gl_lds16(const short* g, short* lds) {
    __builtin_amdgcn_global_load_lds(
        (const __attribute__((address_space(1))) void*)g,
        (__attribute__((address_space(3))) void*)lds, 16, 0, 0);
}

// fast exact-form gelu: Abramowitz-Stegun 7.1.26 erf approx, |err| < 1.5e-7
static __device__ __forceinline__ float gelu_f(float x) {
    float z = x * 0.70710678118f;
    float az = fabsf(z);
    float t = __builtin_amdgcn_rcpf(1.f + 0.3275911f * az);
    float poly = t * (0.254829592f + t * (-0.284496736f + t * (1.421413741f +
                 t * (-1.453152027f + t * 1.061405429f))));
    float e = __expf(-z * z);
    float erfv = 1.f - poly * e;
    erfv = (z < 0.f) ? -erfv : erfv;
    return 0.5f * x * (1.f + erfv);
}

// ------------- fused prep: router (blocks 0..RTR-1, NO atomics) || weight cvt -------------
#define RTR_BLOCKS (NTOK / 4)            // 2048
__global__ __launch_bounds__(256) void prep_k(const float* __restrict__ x,
                                              const float* __restrict__ Wr,
                                              int* __restrict__ a_exp, float* __restrict__ a_w,
                                              short* __restrict__ xb,
                                              const float* __restrict__ W1,
                                              const float* __restrict__ W2,
                                              short* __restrict__ W1b,
                                              short* __restrict__ W2b,
                                              int n8a, int n8tot) {
    if (blockIdx.x >= RTR_BLOCKS) {
        int i = (blockIdx.x - RTR_BLOCKS) * 256 + threadIdx.x;
        if (i >= n8tot) return;
        const float* in; short* out; int j;
        if (i < n8a) { in = W1; out = W1b; j = i; }
        else         { in = W2; out = W2b; j = i - n8a; }
        float4 a = ((const float4*)in)[2 * j];
        float4 b = ((const float4*)in)[2 * j + 1];
        ((short8*)out)[j] = cvt8(a, b);
        return;
    }
    // router: 4 token-waves per block; emits top-2 (a_exp, a_w) + xb. Zero atomics.
    int t = blockIdx.x * 4 + (threadIdx.x >> 6);
    int lane = threadIdx.x & 63;
    const float* xr = x + (size_t)t * DIM;
    short* xbr = xb + (size_t)t * DIM;
    float p[NE];
#pragma unroll
    for (int e = 0; e < NE; ++e) p[e] = 0.f;
    for (int i = 0; i < DIM / 64; ++i) {
        float xv = xr[lane + i * 64];
        xbr[lane + i * 64] = bf16_of(xv);
#pragma unroll
        for (int e = 0; e < NE; ++e) p[e] += xv * Wr[e * DIM + lane + i * 64];
    }
#pragma unroll
    for (int off = 32; off >= 1; off >>= 1)
#pragma unroll
        for (int e = 0; e < NE; ++e) p[e] += __shfl_xor(p[e], off);
    if (lane == 0) {
        float mx = p[0];
#pragma unroll
        for (int e = 1; e < NE; ++e) mx = fmaxf(mx, p[e]);
        float pr[NE]; float s = 0.f;
#pragma unroll
        for (int e = 0; e < NE; ++e) { pr[e] = expf(p[e] - mx); s += pr[e]; }
#pragma unroll
        for (int e = 0; e < NE; ++e) pr[e] /= s;
        int i1 = 0;
#pragma unroll
        for (int e = 1; e < NE; ++e) if (pr[e] > pr[i1]) i1 = e;
        int i2 = (i1 == 0) ? 1 : 0;
#pragma unroll
        for (int e = 0; e < NE; ++e) if (e != i1 && pr[e] > pr[i2]) i2 = e;
        float w1 = pr[i1], w2 = pr[i2], nrm = w1 + w2;
        a_exp[2 * t] = i1;     a_w[2 * t] = w1 / nrm;
        a_exp[2 * t + 1] = i2; a_w[2 * t + 1] = w2 / nrm;
    }
}

// ------- rank_k: deterministic bucketing, single 1024-thread block, no atomics -------
#define RK_T 1024
#define RK_IT (NASSIGN / RK_T)           // 16
__global__ __launch_bounds__(RK_T) void rank_k(const int* __restrict__ a_exp,
                                               int* __restrict__ cnt,
                                               int* __restrict__ offs,
                                               int* __restrict__ ptok,
                                               int* __restrict__ slot_of) {
    __shared__ int s[NE][RK_T];
    __shared__ int cur[NE][RK_T];
    __shared__ int offs_s[NE];
    const int tid = threadIdx.x;
    const int base = tid * RK_IT;
#pragma unroll
    for (int e = 0; e < NE; ++e) s[e][tid] = 0;
    for (int k = 0; k < RK_IT; ++k) s[a_exp[base + k]][tid]++;   // own column, no race
    __syncthreads();
    for (int d = 1; d < RK_T; d <<= 1) {
        int v[NE];
#pragma unroll
        for (int e = 0; e < NE; ++e) v[e] = (tid >= d) ? s[e][tid - d] : 0;
        __syncthreads();
#pragma unroll
        for (int e = 0; e < NE; ++e) s[e][tid] += v[e];
        __syncthreads();
    }
    if (tid == 0) {
        int acc = 0;
#pragma unroll
        for (int e = 0; e < NE; ++e) { offs_s[e] = acc; offs[e] = acc; acc += s[e][RK_T - 1]; }
        offs[NE] = acc;
    }
    if (tid < NE) cnt[tid] = s[tid][RK_T - 1];
    __syncthreads();
#pragma unroll
    for (int e = 0; e < NE; ++e)
        cur[e][tid] = offs_s[e] + ((tid >= 1) ? s[e][tid - 1] : 0);
    for (int k = 0; k < RK_IT; ++k) {
        int a = base + k;
        int e = a_exp[a];
        int r = cur[e][tid]++;
        ptok[r] = a >> 1;
        slot_of[a] = r;
    }
}

// ======== 256x256 grouped GEMM core — rotated read-ahead, 1 vmcnt/K-tile (r9, verified) ========
// LDS: 2 K-tile buffers (A 256x64 + B 256x64 bf16) = 128 KB. 8 waves (2M x 4N).
// Swizzle: LDS[row][slot] = global[row][slot ^ (row&7)]  -> 0 bank conflicts (verified).
// Cross-wave publication: wave X's vmcnt(4) @p2(t) drains Ah0_{t+1},Ba_{t+1}; p2's
// barrier orders every wave's drain before any wave's p4 rotate-reads. LDS WAR windows
// all span >=2 sealed barriers (r9 audit). n0-fast decomposition (r14 lesson).
#define MFMA_BF16 __builtin_amdgcn_mfma_f32_16x16x32_bf16
#define SBAR0 __builtin_amdgcn_sched_barrier(0)
#define LGKM0 asm volatile("s_waitcnt lgkmcnt(0)" ::: "memory")

template <int KROW, int KCH, bool GATHER>
__device__ __forceinline__ void gemm8p(const short* __restrict__ A,
                                       const int* __restrict__ ptok,
                                       const short* __restrict__ B,
                                       int offs_e, int cnt_e, int m0, int n0, int k0,
                                       f32x4 acc[8][4],
                                       short (*As)[16384], short (*Bs)[16384]) {
    const int tid = threadIdx.x;
    const int lane = tid & 63, wave = tid >> 6;
    const int wr = wave >> 2, wc = wave & 3;

#pragma unroll
    for (int m = 0; m < 8; ++m)
#pragma unroll
        for (int n = 0; n < 4; ++n) acc[m][n] = (f32x4){0.f, 0.f, 0.f, 0.f};

    const int srow = tid >> 3, sslot = tid & 7;
    const int gsl8 = (sslot ^ (srow & 7)) * 8;      // inverse-swizzled global 16B slot

    int ra0 = m0 + srow;       if (ra0 >= cnt_e) ra0 = cnt_e - 1;   // Ah0
    int ra2 = m0 + srow + 128; if (ra2 >= cnt_e) ra2 = cnt_e - 1;   // Ah0
    int ra1 = m0 + srow + 64;  if (ra1 >= cnt_e) ra1 = cnt_e - 1;   // Ah1
    int ra3 = m0 + srow + 192; if (ra3 >= cnt_e) ra3 = cnt_e - 1;   // Ah1
    const short* aR0 = A + (GATHER ? (size_t)ptok[offs_e + ra0] : (size_t)(offs_e + ra0)) * KROW + k0 + gsl8;
    const short* aR2 = A + (GATHER ? (size_t)ptok[offs_e + ra2] : (size_t)(offs_e + ra2)) * KROW + k0 + gsl8;
    const short* aR1 = A + (GATHER ? (size_t)ptok[offs_e + ra1] : (size_t)(offs_e + ra1)) * KROW + k0 + gsl8;
    const short* aR3 = A + (GATHER ? (size_t)ptok[offs_e + ra3] : (size_t)(offs_e + ra3)) * KROW + k0 + gsl8;
    const int br = (srow & 31) + (srow >> 5) * 64;
    const short* bRa0 = B + (size_t)(n0 + br) * KROW + k0 + gsl8;
    const short* bRa1 = B + (size_t)(n0 + br + 128) * KROW + k0 + gsl8;
    const short* bRb0 = B + (size_t)(n0 + br + 32) * KROW + k0 + gsl8;
    const short* bRb1 = B + (size_t)(n0 + br + 160) * KROW + k0 + gsl8;
    const int lA0a = tid * 8,                 lA0b = (tid + 1024) * 8;
    const int lA1a = (tid + 512) * 8,         lA1b = (tid + 1536) * 8;
    const int lBaa = (br * 8 + sslot) * 8,    lBab = ((br + 128) * 8 + sslot) * 8;
    const int lBba = ((br + 32) * 8 + sslot) * 8, lBbb = ((br + 160) * 8 + sslot) * 8;

    auto stAh0 = [&](int b, int co) { gl_lds16(aR0 + co, &As[b][lA0a]); gl_lds16(aR2 + co, &As[b][lA0b]); };
    auto stAh1 = [&](int b, int co) { gl_lds16(aR1 + co, &As[b][lA1a]); gl_lds16(aR3 + co, &As[b][lA1b]); };
    auto stBa  = [&](int b, int co) { gl_lds16(bRa0 + co, &Bs[b][lBaa]); gl_lds16(bRa1 + co, &Bs[b][lBab]); };
    auto stBb  = [&](int b, int co) { gl_lds16(bRb0 + co, &Bs[b][lBba]); gl_lds16(bRb1 + co, &Bs[b][lBbb]); };

    const int fr = lane & 15, g4 = lane >> 4, swz = fr & 7;
    const int NK = KCH / 64;

    short8 aF0[2][4], aF1[2][4], bF01[2][2], bF23[2][2];

    auto rdA0 = [&](const short* P) {
#pragma unroll
        for (int ks = 0; ks < 2; ++ks)
#pragma unroll
            for (int m = 0; m < 4; ++m)
                aF0[ks][m] = *(const short8*)&P[((wr * 128 + m * 16 + fr) * 8 + ((ks * 4 + g4) ^ swz)) * 8];
    };
    auto rdA1 = [&](const short* P) {
#pragma unroll
        for (int ks = 0; ks < 2; ++ks)
#pragma unroll
            for (int m = 0; m < 4; ++m)
                aF1[ks][m] = *(const short8*)&P[((wr * 128 + 64 + m * 16 + fr) * 8 + ((ks * 4 + g4) ^ swz)) * 8];
    };
    auto rdB01 = [&](const short* P) {
#pragma unroll
        for (int ks = 0; ks < 2; ++ks)
#pragma unroll
            for (int n = 0; n < 2; ++n)
                bF01[ks][n] = *(const short8*)&P[((wc * 64 + n * 16 + fr) * 8 + ((ks * 4 + g4) ^ swz)) * 8];
    };
    auto rdB23 = [&](const short* P) {
#pragma unroll
        for (int ks = 0; ks < 2; ++ks)
#pragma unroll
            for (int n = 0; n < 2; ++n)
                bF23[ks][n] = *(const short8*)&P[((wc * 64 + (n + 2) * 16 + fr) * 8 + ((ks * 4 + g4) ^ swz)) * 8];
    };

    // prologue: tile0 (4 halves) + tile1's Ah0,Ba; vmcnt(4) covers tile0 entirely
    stAh0(0, 0); stBa(0, 0); stBb(0, 0); stAh1(0, 0);
    if (NK > 1) {
        stAh0(1, 64); stBa(1, 64);
        asm volatile("s_waitcnt vmcnt(4)" ::: "memory");
    } else {
        asm volatile("s_waitcnt vmcnt(0)" ::: "memory");
    }
    SBAR0;
    __builtin_amdgcn_s_barrier();
    rdA0(As[0]); rdB01(Bs[0]);      // tile0 p1 frags (drained by p1's LGKM0)

    for (int t = 0; t < NK; ++t) {
        const int cur = t & 1, nxt = cur ^ 1;
        const short* Ab = As[cur];
        const short* Bb2 = Bs[cur];
        const int co1 = (t + 1) * 64, co2 = (t + 2) * 64;
        const bool pf1 = (t + 1 < NK), pf2 = (t + 2 < NK);

        // ---- P1: MFMA mh0 x n01; read Bn23_t; stage Bb_{t+1} ----
        LGKM0; SBAR0;
        __builtin_amdgcn_s_setprio(1);
#pragma unroll
        for (int ks = 0; ks < 2; ++ks)
#pragma unroll
            for (int m = 0; m < 4; ++m)
#pragma unroll
                for (int n = 0; n < 2; ++n)
                    acc[m][n] = MFMA_BF16(aF0[ks][m], bF01[ks][n], acc[m][n], 0, 0, 0);
        __builtin_amdgcn_s_setprio(0);
        rdB23(Bb2);
        if (pf1) stBb(nxt, co1);
        SBAR0;
        __builtin_amdgcn_s_barrier();

        // ---- P2: MFMA mh0 x n23; read Ah1_t; stage Ah1_{t+1}; vmcnt publishes t+1 ----
        LGKM0; SBAR0;
        __builtin_amdgcn_s_setprio(1);
#pragma unroll
        for (int ks = 0; ks < 2; ++ks)
#pragma unroll
            for (int m = 0; m < 4; ++m)
#pragma unroll
                for (int n = 0; n < 2; ++n)
                    acc[m][n + 2] = MFMA_BF16(aF0[ks][m], bF23[ks][n], acc[m][n + 2], 0, 0, 0);
        __builtin_amdgcn_s_setprio(0);
        rdA1(Ab);
        if (pf1) stAh1(nxt, co1);
        SBAR0;
        __builtin_amdgcn_s_barrier();

        // ---- P3: MFMA mh1 x n01; stage Ah0_{t+2} (into cur) ----
        LGKM0; SBAR0;
        __builtin_amdgcn_s_setprio(1);
#pragma unroll
        for (int ks = 0; ks < 2; ++ks)
#pragma unroll
            for (int m = 0; m < 4; ++m)
#pragma unroll
                for (int n = 0; n < 2; ++n)
                    acc[4 + m][n] = MFMA_BF16(aF1[ks][m], bF01[ks][n], acc[4 + m][n], 0, 0, 0);
        __builtin_amdgcn_s_setprio(0);
        if (pf2) stAh0(cur, co2);
        SBAR0;
        __builtin_amdgcn_s_barrier();

        // ---- P4: MFMA mh1 x n23; stage Ba_{t+2}; vmcnt; read tile t+1 p1 frags ----
        __builtin_amdgcn_s_setprio(1);
#pragma unroll
        for (int ks = 0; ks < 2; ++ks)
#pragma unroll
            for (int m = 0; m < 4; ++m)
#pragma unroll
                for (int n = 0; n < 2; ++n)
                    acc[4 + m][n + 2] = MFMA_BF16(aF1[ks][m], bF23[ks][n], acc[4 + m][n + 2], 0, 0, 0);
        __builtin_amdgcn_s_setprio(0);
        if (pf2) {
            stBa(cur, co2);
            asm volatile("s_waitcnt vmcnt(4)" ::: "memory");
        } else if (pf1) {
            asm volatile("s_waitcnt vmcnt(0)" ::: "memory");
        }
        SBAR0;
        if (pf1) { rdA0(As[nxt]); rdB01(Bs[nxt]); }
        SBAR0;
        __builtin_amdgcn_s_barrier();
    }
}

// ---------------- GEMM1: H = gelu(Xg @ W1[e]^T + b1[e]) ----------------
#define G1_NX (FF / 256)                 // 16
#define G1_NWG (G1_NX * MB_MAX * NE)     // 4096
__global__ __launch_bounds__(512, 2) void gemm1_k(const short* __restrict__ xb,
                                                  const short* __restrict__ W1b,
                                                  const float* __restrict__ b1,
                                                  const int* __restrict__ cnt,
                                                  const int* __restrict__ offs,
                                                  const int* __restrict__ ptok,
                                                  short* __restrict__ H) {
    __shared__ __align__(16) short As[2][16384];
    __shared__ __align__(16) short Bs[2][16384];
    int wg = (blockIdx.x % 8) * (G1_NWG / 8) + blockIdx.x / 8;   // bijective XCD swizzle
    const int n0 = (wg % G1_NX) * 256;  wg /= G1_NX;             // n0 fast (A-panel L2 reuse)
    const int m0 = (wg % MB_MAX) * 256; wg /= MB_MAX;
    const int e = wg;
    const int cnt_e = cnt[e];
    if (m0 >= cnt_e) return;
    const int offs_e = offs[e];

    f32x4 acc[8][4];
    gemm8p<DIM, DIM, true>(xb, ptok, W1b + (size_t)e * FF * DIM, offs_e, cnt_e, m0, n0, 0, acc, As, Bs);

    const int lane = threadIdx.x & 63, wave = threadIdx.x >> 6;
    const int wr = wave >> 2, wc = wave & 3;
    const int colb = lane & 15, rowb = (lane >> 4) * 4;
    float b1v[4];
#pragma unroll
    for (int n = 0; n < 4; ++n) b1v[n] = b1[e * FF + n0 + wc * 64 + n * 16 + colb];
#pragma unroll
    for (int m = 0; m < 8; ++m) {
#pragma unroll
        for (int r = 0; r < 4; ++r) {
            const int gm = m0 + wr * 128 + m * 16 + rowb + r;
            if (gm >= cnt_e) continue;
#pragma unroll
            for (int n = 0; n < 4; ++n) {
                const int col = n0 + wc * 64 + n * 16 + colb;
                float v = gelu_f(acc[m][n][r] + b1v[n]);
                H[(size_t)(offs_e + gm) * FF + col] = bf16_of(v);
            }
        }
    }
}

// ---- GEMM2: ypart(bf16) = H[:, kslice] @ W2[e][:, kslice]^T  (b2 in combine) ----
#define G2_NX (DIM / 256)                // 4
template <int KCH>
__global__ __launch_bounds__(512, 2) void gemm2_k(const short* __restrict__ H,
                                                  const short* __restrict__ W2b,
                                                  const int* __restrict__ cnt,
                                                  const int* __restrict__ offs,
                                                  short* __restrict__ y0,
                                                  short* __restrict__ y1,
                                                  int nwg) {
    __shared__ __align__(16) short As[2][16384];
    __shared__ __align__(16) short Bs[2][16384];
    const int KS = FF / KCH;
    int wg = (blockIdx.x % 8) * (nwg / 8) + blockIdx.x / 8;
    int nk = wg % (G2_NX * KS); wg /= (G2_NX * KS);              // (n,k) fast (A-panel reuse)
    const int n0 = (nk % G2_NX) * 256;
    const int kslice = nk / G2_NX;
    const int m0 = (wg % MB_MAX) * 256; wg /= MB_MAX;
    const int e = wg;
    const int cnt_e = cnt[e];
    if (m0 >= cnt_e) return;
    const int offs_e = offs[e];

    f32x4 acc[8][4];
    gemm8p<FF, KCH, false>(H, nullptr, W2b + (size_t)e * DIM * FF, offs_e, cnt_e, m0, n0,
                           kslice * KCH, acc, As, Bs);

    short* y = kslice ? y1 : y0;
    const int lane = threadIdx.x & 63, wave = threadIdx.x >> 6;
    const int wr = wave >> 2, wc = wave & 3;
    const int colb = lane & 15, rowb = (lane >> 4) * 4;
#pragma unroll
    for (int m = 0; m < 8; ++m) {
#pragma unroll
        for (int r = 0; r < 4; ++r) {
            const int gm = m0 + wr * 128 + m * 16 + rowb + r;
            if (gm >= cnt_e) continue;
#pragma unroll
            for (int n = 0; n < 4; ++n) {
                const int col = n0 + wc * 64 + n * 16 + colb;
                y[(size_t)(offs_e + gm) * DIM + col] = bf16_of(acc[m][n][r]);
            }
        }
    }
}

// -- combine (grid-strided): out[t] = w1*(ysum(s1)+b2[e1]) + w2*(ysum(s2)+b2[e2]) --
__global__ __launch_bounds__(256) void combine_k(const short* __restrict__ y0,
                                                 const short* __restrict__ y1,
                                                 int ks,
                                                 const int* __restrict__ slot_of,
                                                 const int* __restrict__ a_exp,
                                                 const float* __restrict__ a_w,
                                                 const float* __restrict__ b2,
                                                 float* __restrict__ out) {
    const int c = threadIdx.x;          // 256 threads * 4 cols = 1024
    for (int t = blockIdx.x; t < NTOK; t += 2048) {
        const int s1 = slot_of[2 * t], s2 = slot_of[2 * t + 1];
        const int e1 = a_exp[2 * t], e2 = a_exp[2 * t + 1];
        const float w1 = a_w[2 * t], w2 = a_w[2 * t + 1];
        short4v p1 = ((const short4v*)(y0 + (size_t)s1 * DIM))[c];
        short4v p2 = ((const short4v*)(y0 + (size_t)s2 * DIM))[c];
        float v1x = f_of_bf16(p1[0]), v1y = f_of_bf16(p1[1]), v1z = f_of_bf16(p1[2]), v1w = f_of_bf16(p1[3]);
        float v2x = f_of_bf16(p2[0]), v2y = f_of_bf16(p2[1]), v2z = f_of_bf16(p2[2]), v2w = f_of_bf16(p2[3]);
        if (ks == 2) {
            short4v q1 = ((const short4v*)(y1 + (size_t)s1 * DIM))[c];
            short4v q2 = ((const short4v*)(y1 + (size_t)s2 * DIM))[c];
            v1x += f_of_bf16(q1[0]); v1y += f_of_bf16(q1[1]); v1z += f_of_bf16(q1[2]); v1w += f_of_bf16(q1[3]);
            v2x += f_of_bf16(q2[0]); v2y += f_of_bf16(q2[1]); v2z += f_of_bf16(q2[2]); v2w += f_of_bf16(q2[3]);
        }
        float4 g1 = ((const float4*)(b2 + (size_t)e1 * DIM))[c];
        float4 g2 = ((const float4*)(b2 + (size_t)e2 * DIM))[c];
        float4 o;
        o.x = w1 * (v1x + g1.x) + w2 * (v2x + g2.x);
        o.y = w1 * (v1y + g1.y) + w2 * (v2y + g2.y);
        o.z = w1 * (v1z + g1.z) + w2 * (v2z + g2.z);
        o.w = w1 * (v1w + g1.w) + w2 * (v2w + g2.w);
        ((float4*)(out + (size_t)t * DIM))[c] = o;
    }
}

// ---------------- launch ----------------
extern "C" void kernel_launch(void* const* d_in, const int* in_sizes, int n_in,
                              void* d_out, int out_size, void* d_ws, size_t ws_size,
                              hipStream_t stream) {
    const float* x  = (const float*)d_in[0];
    const float* Wr = (const float*)d_in[1];
    const float* W1 = (const float*)d_in[2];
    const float* b1 = (const float*)d_in[3];
    const float* W2 = (const float*)d_in[4];
    const float* b2 = (const float*)d_in[5];
    float* out = (float*)d_out;

    char* w = (char*)d_ws;
    int*   cnt     = (int*)w;                        // 32 B
    int*   offs    = (int*)(w + 64);                 // 36 B
    int*   a_exp   = (int*)(w + 128);
    int*   ptok    = a_exp + NASSIGN;
    int*   slot_of = ptok + NASSIGN;
    float* a_w     = (float*)(slot_of + NASSIGN);
    char*  p       = (char*)(a_w + NASSIGN);
    p = (char*)(((uintptr_t)p + 255) & ~(uintptr_t)255);
    short* xb  = (short*)p;                p += (size_t)NTOK * DIM * 2;
    short* W1b = (short*)p;                p += (size_t)NE * FF * DIM * 2;
    short* W2b = (short*)p;                p += (size_t)NE * DIM * FF * 2;
    short* H   = (short*)p;                p += (size_t)NASSIGN * FF * 2;   // 134 MB
    // y0 aliases W1b (dead after gemm1, 67 MB >= 33.5 MB); y1 gets its own 33.5 MB
    short* y0  = (short*)W1b;
    short* y1  = (short*)p;                p += (size_t)NASSIGN * DIM * 2;
    const int ks = ((size_t)(p - w) <= ws_size) ? 2 : 1;

    const int n8a = NE * FF * DIM / 8, n8tot = n8a + NE * DIM * FF / 8;
    const int prep_blocks = RTR_BLOCKS + (n8tot + 255) / 256;
    prep_k<<<prep_blocks, 256, 0, stream>>>(x, Wr, a_exp, a_w, xb,
                                            W1, W2, W1b, W2b, n8a, n8tot);

    rank_k<<<1, RK_T, 0, stream>>>(a_exp, cnt, offs, ptok, slot_of);

    gemm1_k<<<G1_NWG, 512, 0, stream>>>(xb, W1b, b1, cnt, offs, ptok, H);

    if (ks == 2) {
        const int nwg2 = G2_NX * 2 * MB_MAX * NE;   // 2048
        gemm2_k<FF / 2><<<nwg2, 512, 0, stream>>>(H, W2b, cnt, offs, y0, y1, nwg2);
    } else {
        const int nwg2 = G2_NX * MB_MAX * NE;       // 1024
        gemm2_k<FF><<<nwg2, 512, 0, stream>>>(H, W2b, cnt, offs, y0, y1, nwg2);
    }
    combine_k<<<2048, 256, 0, stream>>>(y0, y1, ks, slot_of, a_exp, a_w, b2, out);
}